// Round 3
// baseline (309.235 us; speedup 1.0000x reference)
//
#include <hip/hip_runtime.h>

// Conv2d via implicit-GEMM MFMA: input (64,8,256,256) f32, filter (8,8,3,3)
// OIHW, VALID, stride 1 -> out (64,8,254,254) f32.
//
// mfma_f32_16x16x32_f16: M = output channel m (8 valid of 16),
// N = 16 consecutive x pixels (fixed y), K = 96 = 3 chunks of 32.
// Semantic k-slot: chunk kk, lane-group g=(lane>>4), elem j:
//   q = kk*4+g (q = r*3+s, valid q<=8), c = j. A zeroed for q>8 / m>=8.
//
// Round-3 change: pipelined y-walk. Each block owns a 64x64 output strip
// (4 y-steps of 16 rows) and double-buffers the LDS input tile:
//   per step t: cvt+ds_write(t) -> barrier -> issue ALL 40 loads(t+1) into
//   regs -> compute(t) (48 MFMA + stores). Loads for t+1 fly under compute(t)
//   -- one vmcnt epoch per step instead of five serialized ones (VGPR=20
//   in round 2 forced 5x ~1000-cycle exposed-latency epochs per block).
// LDS: 2 x [18 rows][66 x][8 c] f16 channel-last = 38016 B -> 4 blocks/CU,
// grid 1024 = exactly 4/CU, zero tail. One barrier per step (write(t+2) is
// fenced from compute(t) readers by barrier(t+1)).

#define XW 66
#define ROWS 18
#define CELLS (ROWS * XW)   // 1188

typedef _Float16 half8 __attribute__((ext_vector_type(8)));
typedef float floatx4 __attribute__((ext_vector_type(4)));

__global__ __launch_bounds__(256, 4)
void conv2d_mfma_kernel(const float* __restrict__ inp,
                        const float* __restrict__ filt,
                        float* __restrict__ out) {
    __shared__ __align__(16) _Float16 s_in[2][CELLS * 8];  // 38016 B

    const int tid = threadIdx.x;
    const int x0     = blockIdx.x * 64;   // 0,64,128,192
    const int ystrip = blockIdx.y * 64;   // 0,64,128,192
    const int n      = blockIdx.z;

    const float* in_n  = inp + (size_t)n * (8 * 256 * 256);
    float*       out_n = out + (size_t)n * (8 * 254 * 254);

    // ---- staging descriptors: 5 cells per thread over 18x66 ----
    int  srow[5], sgx[5];
    bool sok[5];
    #pragma unroll
    for (int i = 0; i < 5; ++i) {
        int  idx = tid + i * 256;
        bool act = idx < CELLS;
        int  ci  = act ? idx : 0;
        srow[i] = ci / XW;
        int col = ci - srow[i] * XW;
        sgx[i]  = x0 + col;
        sok[i]  = act && (sgx[i] < 256);
    }

    float v[5][8];
    auto issue_loads = [&](int t) {
        const int ybase = ystrip + t * 16;
        #pragma unroll
        for (int i = 0; i < 5; ++i) {
            const int  iy = ybase + srow[i];
            const bool ok = sok[i] && (iy < 256);
            const float* p = in_n + iy * 256 + sgx[i];
            #pragma unroll
            for (int c = 0; c < 8; ++c)
                v[i][c] = ok ? p[c * 65536] : 0.0f;   // 256*256 plane stride
        }
    };

    issue_loads(0);   // start HBM traffic before anything else

    const int lane = tid & 63;
    const int w    = tid >> 6;     // wave 0..3
    const int lx   = lane & 15;    // A: row m ; B/D: col pixel
    const int g    = lane >> 4;    // k-slot group / D row group

    // ---- A-fragments (filter), once per block; 2.3 KB, L2-hot ----
    half8 afrag[3];
    int   dcell[3];
    #pragma unroll
    for (int kk = 0; kk < 3; ++kk) {
        int q  = kk * 4 + g;               // 0..11
        int qa = q > 8 ? 8 : q;            // clamp for address only
        int r  = qa / 3;
        int s2 = qa - r * 3;
        dcell[kk] = r * XW + s2;
        half8 a = {};
        if (q <= 8 && lx < 8) {
            #pragma unroll
            for (int j = 0; j < 8; ++j)    // filt[m][c][r][s] = m*72 + c*9 + q
                a[j] = (_Float16)filt[lx * 72 + j * 9 + q];
        }
        afrag[kk] = a;
    }

    // ---- pipelined y-walk: 4 steps of 16 output rows ----
    #pragma unroll
    for (int t = 0; t < 4; ++t) {
        const int s = t & 1;

        // cvt + write stage t (waits on its own loads only)
        #pragma unroll
        for (int i = 0; i < 5; ++i) {
            if (i < 4 || tid < CELLS - 1024) {
                half8 h;
                #pragma unroll
                for (int c = 0; c < 8; ++c) h[c] = (_Float16)v[i][c];
                *reinterpret_cast<half8*>(&s_in[s][(tid + i * 256) * 8]) = h;
            }
        }
        __syncthreads();

        // issue next step's loads; they complete under compute(t)
        if (t < 3) {
            issue_loads(t + 1);
            __builtin_amdgcn_sched_barrier(0);   // pin loads before compute
        }

        // compute step t from s_in[s]: per wave 4 y-rows x 4 x-groups
        #pragma unroll
        for (int yy = 0; yy < 4; ++yy) {
            const int y       = w * 4 + yy;
            const int rowbase = y * XW + lx;
            floatx4 acc[4] = {{0,0,0,0},{0,0,0,0},{0,0,0,0},{0,0,0,0}};
            #pragma unroll
            for (int kk = 0; kk < 3; ++kk) {
                #pragma unroll
                for (int xg = 0; xg < 4; ++xg) {
                    const half8 b = *reinterpret_cast<const half8*>(
                        &s_in[s][(rowbase + xg * 16 + dcell[kk]) * 8]);
                    acc[xg] = __builtin_amdgcn_mfma_f32_16x16x32_f16(
                                  afrag[kk], b, acc[xg], 0, 0, 0);
                }
            }
            // D layout: col = lane&15 (pixel), row = g*4 + i (m; valid g<2)
            const int oy = ystrip + t * 16 + y;
            if (g < 2 && oy < 254) {
                const int offy = oy * 254;
                #pragma unroll
                for (int xg = 0; xg < 4; ++xg) {
                    const int ox = x0 + xg * 16 + lx;
                    if (ox < 254) {
                        float* op = out_n + (g * 4) * 64516 + offy + ox;
                        #pragma unroll
                        for (int i = 0; i < 4; ++i)
                            op[i * 64516] = acc[xg][i];   // 64516 = 254*254
                    }
                }
            }
        }
        // no trailing barrier needed: write(t+2) is fenced from compute(t)'s
        // readers by barrier(t+1) (each wave computes(t) before reaching it)
    }
}

extern "C" void kernel_launch(void* const* d_in, const int* in_sizes, int n_in,
                              void* d_out, int out_size, void* d_ws, size_t ws_size,
                              hipStream_t stream) {
    const float* inp  = (const float*)d_in[0];   // (64,8,256,256)
    const float* filt = (const float*)d_in[1];   // (8,8,3,3)
    float* outp = (float*)d_out;                 // (64,8,254,254)

    dim3 grid(4, 4, 64);
    dim3 block(256);
    conv2d_mfma_kernel<<<grid, block, 0, stream>>>(inp, filt, outp);
}

// Round 4
// 306.833 us; speedup vs baseline: 1.0078x; 1.0078x over previous
//
#include <hip/hip_runtime.h>

// Conv2d via implicit-GEMM MFMA: input (64,8,256,256) f32, filter (8,8,3,3)
// OIHW, VALID, stride 1 -> out (64,8,254,254) f32.
//
// mfma_f32_16x16x32_f16: M = output channel m (8 valid of 16),
// N = 16 consecutive x pixels (fixed y), K = 96 = 3 chunks of 32.
// Semantic k-slot: chunk kk, lane-group g=(lane>>4), elem j:
//   q = kk*4+g (q = r*3+s, valid q<=8), c = j. A zeroed for q>8 / m>=8.
// (identical convention to the round-2/3 kernel, which passed refcheck)
//
// Round-4 change: FULL-WIDTH blocks. Rounds 0/2/3 all plateaued at ~1.9 TB/s
// moving the minimum 245 MB -- 64-px x-tiles slice every 1 KB DRAM plane-row
// into 4 pieces consumed by different blocks/XCDs at different times (and
// stores were 64 B segments) => HBM row-buffer thrash. Now each block owns
// the full 256-px width and a 32-row y-strip, walked in 4-row steps with a
// 3-slot LDS ring:
//   step t: issue loads(chunk t+2) -> compute rows 4t..4t+3 from slots
//   t%3,(t+1)%3 -> cvt+write chunk t+2 into slot (t+2)%3 -> barrier.
// Loads/stores are per-plane sequential KB-scale streams; load latency hides
// under compute. LDS 3x16KB ring; grid = 8 strips x 64 n = 512 blocks.

#define SLOT_HALFS (4 * 256 * 8)   // 8192 halfs = 16 KB per 4-row slot

typedef _Float16 half8 __attribute__((ext_vector_type(8)));
typedef float floatx4 __attribute__((ext_vector_type(4)));

__global__ __launch_bounds__(256, 3)
void conv2d_mfma_kernel(const float* __restrict__ inp,
                        const float* __restrict__ filt,
                        float* __restrict__ out) {
    __shared__ __align__(16) _Float16 s_in[3 * SLOT_HALFS + 64];  // 49280 B

    const int tid    = threadIdx.x;
    const int ystrip = blockIdx.x * 32;   // 0,32,...,224
    const int n      = blockIdx.y;

    const float* in_n  = inp + (size_t)n * (8 * 256 * 256);
    float*       out_n = out + (size_t)n * (8 * 254 * 254);

    const int lane = tid & 63;
    const int w    = tid >> 6;     // wave 0..3  -> output row within step
    const int lx   = lane & 15;    // A: row m ; B/D: col pixel
    const int g    = lane >> 4;    // k-slot group / D row group

    // ---- A-fragments (filter), once per block; 2.3 KB, L2-hot ----
    half8 afrag[3];
    int roff[3], soff[3];
    #pragma unroll
    for (int kk = 0; kk < 3; ++kk) {
        int q  = kk * 4 + g;               // 0..11
        int qa = q > 8 ? 8 : q;            // clamp for address only
        roff[kk] = qa / 3;
        soff[kk] = qa - roff[kk] * 3;
        half8 a = {};
        if (q <= 8 && lx < 8) {
            #pragma unroll
            for (int j = 0; j < 8; ++j)    // filt[m][c][r][s] = m*72 + c*9 + q
                a[j] = (_Float16)filt[lx * 72 + j * 9 + q];
        }
        afrag[kk] = a;
    }

    // ---- chunk staging: chunk ck = input strip-rows 4ck..4ck+3, full width.
    // Thread's cells: (row k, x = tid). Wave-instr = 256 B contiguous; the 4
    // waves cover each 1 KB plane-row back-to-back => sequential DRAM streams.
    float v[4][8];
    auto load_chunk = [&](int ck) {
        #pragma unroll
        for (int k = 0; k < 4; ++k) {
            const int  iy = ystrip + ck * 4 + k;
            const bool ok = iy < 256;
            const float* p = in_n + iy * 256 + tid;
            #pragma unroll
            for (int c = 0; c < 8; ++c)
                v[k][c] = ok ? p[c * 65536] : 0.0f;   // 256*256 plane stride
        }
    };
    auto write_chunk = [&](int ck) {
        _Float16* base = &s_in[(ck % 3) * SLOT_HALFS];
        #pragma unroll
        for (int k = 0; k < 4; ++k) {
            half8 h;
            #pragma unroll
            for (int c = 0; c < 8; ++c) h[c] = (_Float16)v[k][c];
            *reinterpret_cast<half8*>(&base[(k * 256 + tid) * 8]) = h;
        }
    };

    load_chunk(0); write_chunk(0);
    load_chunk(1); write_chunk(1);
    __syncthreads();

    // ---- pipelined y-walk: 8 steps of 4 output rows ----
    for (int t = 0; t < 8; ++t) {
        if (t < 7) load_chunk(t + 2);   // in flight under compute(t)

        const int ro = t * 4 + w;       // this wave's output row (strip-local)
        const int oy = ystrip + ro;

        // per-kk LDS base (byte-exact via half index); row L = ro + roff[kk]
        const _Float16* bptr[3];
        #pragma unroll
        for (int kk = 0; kk < 3; ++kk) {
            int L    = ro + roff[kk];
            int slot = (L >> 2) % 3;
            bptr[kk] = &s_in[slot * SLOT_HALFS +
                             ((L & 3) * 256 + lx + soff[kk]) * 8];
        }

        const bool do_store = (g < 2) && (oy < 254);
        #pragma unroll
        for (int xg = 0; xg < 16; ++xg) {
            floatx4 acc = {0.0f, 0.0f, 0.0f, 0.0f};
            #pragma unroll
            for (int kk = 0; kk < 3; ++kk) {
                const half8 b =
                    *reinterpret_cast<const half8*>(bptr[kk] + xg * 128);
                acc = __builtin_amdgcn_mfma_f32_16x16x32_f16(
                          afrag[kk], b, acc, 0, 0, 0);
            }
            // D: col = lane&15 (pixel), row = g*4 + i (m; valid g<2)
            const int ox = xg * 16 + lx;
            if (do_store && ox < 254) {
                float* op = out_n + (g * 4) * 64516 + oy * 254 + ox;
                #pragma unroll
                for (int i = 0; i < 4; ++i)
                    op[i * 64516] = acc[i];   // 64516 = 254*254
            }
        }

        if (t < 7) write_chunk(t + 2);  // into slot (t+2)%3 == (t-1)%3
        __syncthreads();                // fences write vs next compute AND
                                        // prev readers vs this write
    }
}

extern "C" void kernel_launch(void* const* d_in, const int* in_sizes, int n_in,
                              void* d_out, int out_size, void* d_ws, size_t ws_size,
                              hipStream_t stream) {
    const float* inp  = (const float*)d_in[0];   // (64,8,256,256)
    const float* filt = (const float*)d_in[1];   // (8,8,3,3)
    float* outp = (float*)d_out;                 // (64,8,254,254)

    dim3 grid(8, 64, 1);
    dim3 block(256);
    conv2d_mfma_kernel<<<grid, block, 0, stream>>>(inp, filt, outp);
}

// Round 5
// 258.291 us; speedup vs baseline: 1.1972x; 1.1879x over previous
//
#include <hip/hip_runtime.h>

// Conv2d via implicit-GEMM MFMA: input (64,8,256,256) f32, filter (8,8,3,3)
// OIHW, VALID, stride 1 -> out (64,8,254,254) f32.
//
// mfma_f32_16x16x32_f16: M = out-channel m (8 valid of 16), N = 16 px,
// K = 96 = 3 chunks of 32. k-slot (g=lane>>4, j): q = kk*4+g (q=r*3+s,
// valid q<=8), c = j. A zeroed for q>8 / m>=8. Same convention as the
// refcheck-passed round-2/3/4 kernels.
//
// Round-5 change: WIDE DENSE VMEM everywhere (rounds 0-4 all moved HBM
// traffic as 4 B/lane dwords and plateaued at 1.4-1.9 TB/s; G13/m12-m17:
// narrow loads cost 2-2.5x on memory-bound kernels).
//  - loads: float4/lane, one 1 KB-contiguous wave-instr per input row.
//  - input transpose in LDS: thread writes 4x half8; pixel-quad slot is
//    XOR-swizzled (chunk = i ^ (x4&3) ^ ((x4>>2)&3)) -> structural-floor
//    bank behavior on write AND read; read swizzle folds into per-lane
//    offsets precomputed once per block, xg*256 rides the ds offset imm.
//  - stores: acc -> per-wave LDS out-buffer (no barrier needed) -> dense
//    full-wave float2 stores (512 B/instr, 8 B-aligned 1016 B rows).
// LDS: 3-slot input ring 3x16 KB + 4x8 KB per-wave out-buf = 80 KB
// -> exactly 2 blocks/CU. Grid = 8 y-strips x 64 n = 512 blocks.

typedef _Float16 half8 __attribute__((ext_vector_type(8)));
typedef float floatx4 __attribute__((ext_vector_type(4)));

#define SLOT_H 8192   // halfs per 4-row slot (4 rows * 256 px * 8 c = 16 KB)

__global__ __launch_bounds__(256, 2)
void conv2d_mfma_kernel(const float* __restrict__ inp,
                        const float* __restrict__ filt,
                        float* __restrict__ out) {
    __shared__ __align__(16) _Float16 s_in[3 * SLOT_H];   // 49152 B
    __shared__ __align__(16) float    s_out[4 * 2048];    // 32768 B

    const int tid    = threadIdx.x;
    const int ystrip = blockIdx.x * 32;   // 0,32,...,224
    const int n      = blockIdx.y;

    const float* in_n  = inp + (size_t)n * (8 * 256 * 256);
    float*       out_n = out + (size_t)n * (8 * 254 * 254);

    const int lane = tid & 63;
    const int w    = tid >> 6;    // wave 0..3 (also: staging row 0..3)
    const int lx   = lane & 15;   // A: row m ; B/D: col pixel
    const int g    = lane >> 4;   // k-slot group / D row group
    const int lx4  = tid & 63;    // staging: float4 index within row

    // ---- A-fragments + swizzled per-lane read offsets (once per block) ----
    half8 afrag[3];
    int   roff[3];
    int   loH[3][4];   // half-index offset within a row, per kk per (xg&3)
    #pragma unroll
    for (int kk = 0; kk < 3; ++kk) {
        int q  = kk * 4 + g;                 // 0..11
        int qa = q > 8 ? 8 : q;              // clamp for address only
        roff[kk] = qa / 3;
        int soff = qa - roff[kk] * 3;
        int q0   = lx + soff;                // 0..17: pixel offset in 16-grp
        int e    = (q0 & 3) ^ ((q0 >> 2) & 3);
        int q0b  = q0 >> 4;                  // 0/1: crosses into next group
        int baseH = (q0 >> 2) * 32;          // quad slot, halfs
        #pragma unroll
        for (int j = 0; j < 4; ++j)          // j = xg & 3
            loH[kk][j] = baseH + ((e ^ ((j + q0b) & 3)) << 3);
        half8 a = {};
        if (q <= 8 && lx < 8) {
            #pragma unroll
            for (int j = 0; j < 8; ++j)      // filt[m][c][r][s] = m*72+c*9+q
                a[j] = (_Float16)filt[lx * 72 + j * 9 + q];
        }
        afrag[kk] = a;
    }

    // ---- staging: chunk ck = strip rows 4ck..4ck+3, full width ----
    float4 vv[8];   // this thread's float4 of each channel (row w, x 4*lx4)
    auto load_chunk = [&](int ck) {          // 8 x 1 KB-wide wave loads
        const int iy = ystrip + ck * 4 + w;
        if (iy < 256) {
            const float* p = in_n + iy * 256 + lx4 * 4;
            #pragma unroll
            for (int c = 0; c < 8; ++c)
                vv[c] = *reinterpret_cast<const float4*>(p + c * 65536);
        } else {
            #pragma unroll
            for (int c = 0; c < 8; ++c) vv[c] = make_float4(0.f,0.f,0.f,0.f);
        }
    };
    auto write_chunk = [&](int ck) {         // 4 x swizzled half8 writes
        _Float16* base = &s_in[(ck % 3) * SLOT_H + w * 2048 + lx4 * 32];
        const int sw = (lx4 & 3) ^ ((lx4 >> 2) & 3);
        #pragma unroll
        for (int i = 0; i < 4; ++i) {
            half8 h;
            #pragma unroll
            for (int c = 0; c < 8; ++c) h[c] = (_Float16)vv[c][i];
            *reinterpret_cast<half8*>(base + ((i ^ sw) << 3)) = h;
        }
    };

    load_chunk(0); write_chunk(0);
    load_chunk(1); write_chunk(1);
    __syncthreads();

    // ---- pipelined y-walk: 8 steps of 4 output rows ----
    for (int t = 0; t < 8; ++t) {
        if (t < 7) load_chunk(t + 2);        // fly under compute(t)
        __builtin_amdgcn_sched_barrier(0);   // pin load issue before compute

        const int ro = t * 4 + w;            // this wave's strip-local row
        const int oy = ystrip + ro;

        // per-step swizzled LDS read addresses (halfs)
        int ab[3][4];
        #pragma unroll
        for (int kk = 0; kk < 3; ++kk) {
            int L    = ro + roff[kk];        // input row needed
            int rbH  = ((L >> 2) % 3) * SLOT_H + (L & 3) * 2048;
            #pragma unroll
            for (int j = 0; j < 4; ++j) ab[kk][j] = rbH + loH[kk][j];
        }

        const bool do_out = (g < 2) && (oy < 254);
        #pragma unroll
        for (int xg = 0; xg < 16; ++xg) {
            floatx4 acc = {0.f, 0.f, 0.f, 0.f};
            #pragma unroll
            for (int kk = 0; kk < 3; ++kk) {
                const half8 b = *reinterpret_cast<const half8*>(
                    &s_in[ab[kk][xg & 3] + xg * 128]);
                acc = __builtin_amdgcn_mfma_f32_16x16x32_f16(
                          afrag[kk], b, acc, 0, 0, 0);
            }
            // D: col = lane&15 (px), row = g*4+i (m; valid g<2).
            // Stage into this wave's out-buffer (2-way bank = free).
            if (do_out) {
                #pragma unroll
                for (int i = 0; i < 4; ++i)
                    s_out[w * 2048 + (g * 4 + i) * 256 + xg * 16 + lx] = acc[i];
            }
        }

        // dense full-wave stores from the per-wave buffer (no barrier:
        // writes and reads are within this wave; compiler orders via lgkmcnt)
        if (oy < 254) {
            #pragma unroll
            for (int m = 0; m < 8; ++m) {
                float4 q4 = *reinterpret_cast<const float4*>(
                    &s_out[w * 2048 + m * 256 + lane * 4]);
                float* op = out_n + (size_t)m * 64516 + oy * 254 + lane * 4;
                *reinterpret_cast<float2*>(op) = make_float2(q4.x, q4.y);
                if (lane < 63)   // px 254/255 of the 256-wide tile are invalid
                    *reinterpret_cast<float2*>(op + 2) = make_float2(q4.z, q4.w);
            }
        }

        if (t < 7) write_chunk(t + 2);       // into slot (t+2)%3 (safe: only
        __syncthreads();                     // chunks t,t+1 are read this step)
    }
}

extern "C" void kernel_launch(void* const* d_in, const int* in_sizes, int n_in,
                              void* d_out, int out_size, void* d_ws, size_t ws_size,
                              hipStream_t stream) {
    const float* inp  = (const float*)d_in[0];   // (64,8,256,256)
    const float* filt = (const float*)d_in[1];   // (8,8,3,3)
    float* outp = (float*)d_out;                 // (64,8,254,254)

    dim3 grid(8, 64, 1);
    dim3 block(256);
    conv2d_mfma_kernel<<<grid, block, 0, stream>>>(inp, filt, outp);
}